// Round 5
// baseline (35.732 us; speedup 1.0000x reference)
//
#include <hip/hip_runtime.h>
#include <stdint.h>

// Problem constants
constexpr int T = 2048;
constexpr int B = 8;
constexpr int C = 1024;
constexpr int H = 16;
constexpr int K = 31;
constexpr int BC = B * C;           // 8192, stride between time steps
constexpr int HALO = K - 1;         // 30

// Pipeline tiling: each WAVE owns 64 channels and walks NCH chunks of TT
// time steps with a private double-buffered LDS tile. No __syncthreads.
constexpr int TT = 16;              // time steps per chunk
constexpr int NCH = 4;              // chunks per block (software pipeline)
constexpr int SEG = TT * NCH;       // 64 time steps per block
constexpr int BLOCK = 256;
constexpr int NSLICE = BC / BLOCK;  // 32 channel slices
constexpr int NSEG = T / SEG;       // 32 time segments
constexpr int NBLK = NSLICE * NSEG; // 1024 blocks -> 4/CU

constexpr int DMA_PER_CHUNK = TT / 4;  // 4 global_load_lds (1KB each) per chunk
static_assert(DMA_PER_CHUNK == 4, "vmcnt literals below assume 4 DMA/chunk");
static_assert(TT == 16, "vmcnt literals below assume 16 stores/chunk");

typedef const __attribute__((address_space(1))) uint32_t gas_u32;
typedef __attribute__((address_space(3))) uint32_t las_u32;

// ---------------------------------------------------------------------------
// out[t,b,c] = sum_{d=0..K-1} softmax(w[h])[K-1-d] * x[t-d,b,c] + bias[c]
// ---------------------------------------------------------------------------
__global__ __launch_bounds__(BLOCK, 4) void lconv_tbc_kernel(
        const float* __restrict__ x,
        const float* __restrict__ w,
        const float* __restrict__ bias,
        float* __restrict__ out) {
    // Per-wave private double buffer: [wave][buf][time][chan] = 32 KiB total.
    __shared__ float lds[4][2][TT][64];

    const int tid = threadIdx.x;
    const int wid = tid >> 6;
    const int lane = tid & 63;
    const int slice = blockIdx.x & (NSLICE - 1);
    const int seg = blockIdx.x >> 5;            // log2(NSLICE) = 5
    const int bc0w = slice * BLOCK + wid * 64;  // wave's channel base
    const int bc = bc0w + lane;
    const int c = bc & (C - 1);
    const int h = __builtin_amdgcn_readfirstlane(c >> 6);  // wave-uniform head
    const int ts0 = seg * SEG;                  // first output time

    // ---- Prologue loads FIRST (so they precede DMA(0) in vmcnt order) ----
    // Per-wave softmax of this head's taps.
    float wv[K];
    float m = -1e30f;
    #pragma unroll
    for (int k = 0; k < K; ++k) {
        wv[k] = w[h * K + k];
        m = fmaxf(m, wv[k]);
    }
    float s = 0.0f;
    #pragma unroll
    for (int k = 0; k < K; ++k) {
        wv[k] = __expf(wv[k] - m);
        s += wv[k];
    }
    const float inv = 1.0f / s;
    float wr[K];   // reversed, forced wave-uniform -> SGPRs
    #pragma unroll
    for (int d = 0; d < K; ++d)
        wr[d] = __uint_as_float(
            __builtin_amdgcn_readfirstlane(__float_as_uint(wv[K - 1 - d] * inv)));
    const float bi = bias[c];

    // Halo registers: halo[j] = x[ts0 - 30 + j]
    float halo[HALO];
    if (seg == 0) {
        #pragma unroll
        for (int j = 0; j < HALO; ++j) halo[j] = 0.0f;
    } else {
        #pragma unroll
        for (int j = 0; j < HALO; ++j)
            halo[j] = x[(ts0 - HALO + j) * BC + bc];
    }

    // Per-lane DMA source offset (elements): instr i covers rows 4i..4i+3,
    // lane l -> row 4i + (l>>4), cols (l&15)*4.. (dest = uniform base + l*16).
    const int dma_off = (lane >> 4) * BC + bc0w + (lane & 15) * 4;

    // ---- Issue DMA for chunk 0 ----
    #pragma unroll
    for (int i = 0; i < DMA_PER_CHUNK; ++i)
        __builtin_amdgcn_global_load_lds(
            (gas_u32*)(x + (ts0 + 4 * i) * BC + dma_off),
            (las_u32*)&lds[wid][0][4 * i][0], 16, 0, 0);

    // ---- Pipelined chunk loop (fully unrolled, no barriers) ----
    #pragma unroll
    for (int k = 0; k < NCH; ++k) {
        const int t0 = ts0 + k * TT;

        // Issue DMA for chunk k+1 into the other buffer.
        if (k + 1 < NCH) {
            #pragma unroll
            for (int i = 0; i < DMA_PER_CHUNK; ++i)
                __builtin_amdgcn_global_load_lds(
                    (gas_u32*)(x + (t0 + TT + 4 * i) * BC + dma_off),
                    (las_u32*)&lds[wid][(k + 1) & 1][4 * i][0], 16, 0, 0);
        }

        // Counted wait for chunk k's DMA (in-order retire suffix property):
        // VMEM ops issued after DMA(k) = stores(k-1)[16] + DMA(k+1)[4].
        if (k == 0)           asm volatile("s_waitcnt vmcnt(4)" ::: "memory");
        else if (k + 1 < NCH) asm volatile("s_waitcnt vmcnt(20)" ::: "memory");
        else                  asm volatile("s_waitcnt vmcnt(16)" ::: "memory");

        // Wave-private LDS -> registers (lane-consecutive: 2-way, free).
        float cur[TT];
        #pragma unroll
        for (int r = 0; r < TT; ++r) cur[r] = lds[wid][k & 1][r][lane];

        // 16 outputs x 31 FMAs, all indices static.
        #pragma unroll
        for (int u = 0; u < TT; ++u) {
            float acc = bi;
            #pragma unroll
            for (int d = 0; d < K; ++d) {
                const int j = u - d;
                const float v = (j >= 0) ? cur[j] : halo[HALO + j];
                acc = fmaf(wr[d], v, acc);
            }
            __builtin_nontemporal_store(acc, &out[(t0 + u) * BC + bc]);
        }

        // Slide halo: next chunk needs times [t0+TT-HALO, t0+TT-1].
        if (k + 1 < NCH) {
            float nh[HALO];
            #pragma unroll
            for (int j = 0; j < HALO; ++j) {
                const int tj = j - (HALO - TT);   // index into cur
                nh[j] = (tj >= 0) ? cur[tj] : halo[j + TT];
            }
            #pragma unroll
            for (int j = 0; j < HALO; ++j) halo[j] = nh[j];
        }
    }
}

extern "C" void kernel_launch(void* const* d_in, const int* in_sizes, int n_in,
                              void* d_out, int out_size, void* d_ws, size_t ws_size,
                              hipStream_t stream) {
    const float* x = (const float*)d_in[0];      // [T, B, C]
    const float* w = (const float*)d_in[1];      // [H, 1, K]
    const float* bias = (const float*)d_in[2];   // [C]
    float* out = (float*)d_out;                  // [T, B, C]

    lconv_tbc_kernel<<<dim3(NBLK), dim3(BLOCK), 0, stream>>>(x, w, bias, out);
}

// Round 6
// 32.494 us; speedup vs baseline: 1.0997x; 1.0997x over previous
//
#include <hip/hip_runtime.h>
#include <stdint.h>

// Problem constants
constexpr int T = 2048;
constexpr int B = 8;
constexpr int C = 1024;
constexpr int H = 16;
constexpr int K = 31;
constexpr int BC = B * C;            // 8192, stride between time steps

// Tiling: whole chunk window in registers, one load batch per thread.
constexpr int TT = 32;               // outputs per thread
constexpr int NB = K - 1 + TT;       // 61 window registers
constexpr int BLOCK = 256;
constexpr int BLK_PER_CHUNK = BC / BLOCK;    // 32
constexpr int NCHUNK = T / TT;               // 64
constexpr int NBLK = BLK_PER_CHUNK * NCHUNK; // 2048

// ---------------------------------------------------------------------------
// out[t,b,c] = sum_{d=0..K-1} wr[d] * x[t-d, b, c] + bias[c]
// wr[d] = softmax(w[h])[K-1-d], wave-uniform -> SGPRs.
//
// Key structural device: the entire 61-deep load batch is issued BEFORE a
// __builtin_amdgcn_sched_barrier(0), which the scheduler cannot cross. This
// prevents the pressure-driven load sinking that collapsed R2/R3/R5 to
// 40-44 VGPRs and ~8 serial load->use latency exposures per thread. With the
// batch in flight, there is ONE exposed latency; the per-use s_waitcnt
// vmcnt(N) then drains oldest-first as u ascends.
// ---------------------------------------------------------------------------
__global__ __launch_bounds__(BLOCK, 4) void lconv_tbc_kernel(
        const float* __restrict__ x,
        const float* __restrict__ w,
        const float* __restrict__ bias,
        float* __restrict__ out) {
    const int tid = threadIdx.x;
    const int cb = blockIdx.x & (BLK_PER_CHUNK - 1);   // bc slice
    const int chunk = blockIdx.x / BLK_PER_CHUNK;      // time chunk
    const int bc = cb * BLOCK + tid;                   // [0, BC)
    const int c = bc & (C - 1);
    // Each 64-lane wave spans exactly one head (c0 multiple of 64, G=64):
    const int h = __builtin_amdgcn_readfirstlane(c >> 6);

    const int t0 = chunk * TT;
    const int base = t0 * BC + bc;   // element index; max ~16.8M fits int

    // ---- Issue the ENTIRE window as one load batch ----
    float buf[NB];
    if (chunk == 0) {
        #pragma unroll
        for (int j = 0; j < K - 1; ++j) buf[j] = 0.0f;
    } else {
        #pragma unroll
        for (int j = 0; j < K - 1; ++j)
            buf[j] = x[base + (j - (K - 1)) * BC];
    }
    #pragma unroll
    for (int u = 0; u < TT; ++u)
        buf[K - 1 + u] = x[base + u * BC];

    // ---- Softmax of this head's taps overlaps the loads (VALU-only) ----
    float wv[K];
    float m = -1e30f;
    #pragma unroll
    for (int k = 0; k < K; ++k) {
        wv[k] = w[h * K + k];
        m = fmaxf(m, wv[k]);
    }
    float s = 0.0f;
    #pragma unroll
    for (int k = 0; k < K; ++k) {
        wv[k] = __expf(wv[k] - m);
        s += wv[k];
    }
    const float inv = 1.0f / s;
    // Reversed weights, forced wave-uniform -> SGPRs:
    float wr[K];
    #pragma unroll
    for (int d = 0; d < K; ++d)
        wr[d] = __uint_as_float(
            __builtin_amdgcn_readfirstlane(__float_as_uint(wv[K - 1 - d] * inv)));
    const float bi = bias[c];

    // ---- HARD boundary: nothing below may be hoisted above, no load may
    // sink below. All 61 window loads are now in flight. ----
    __builtin_amdgcn_sched_barrier(0);

    // ---- 32 outputs x 31 FMAs, all register indices static; u ascending
    // so each vmcnt wait drains the oldest outstanding loads first. ----
    #pragma unroll
    for (int u = 0; u < TT; ++u) {
        float acc = bi;
        #pragma unroll
        for (int d = 0; d < K; ++d)
            acc = fmaf(wr[d], buf[K - 1 + u - d], acc);
        __builtin_nontemporal_store(acc, &out[base + u * BC]);
    }
}

extern "C" void kernel_launch(void* const* d_in, const int* in_sizes, int n_in,
                              void* d_out, int out_size, void* d_ws, size_t ws_size,
                              hipStream_t stream) {
    const float* x = (const float*)d_in[0];      // [T, B, C]
    const float* w = (const float*)d_in[1];      // [H, 1, K]
    const float* bias = (const float*)d_in[2];   // [C]
    float* out = (float*)d_out;                  // [T, B, C]

    lconv_tbc_kernel<<<dim3(NBLK), dim3(BLOCK), 0, stream>>>(x, w, bias, out);
}